// Round 1
// 1773.939 us; speedup vs baseline: 1.0233x; 1.0233x over previous
//
#include <hip/hip_runtime.h>
#include <hip/hip_bf16.h>

typedef __bf16 bf16_t;
typedef __bf16 bf16x4 __attribute__((ext_vector_type(4)));
typedef __bf16 bf16x8 __attribute__((ext_vector_type(8)));
typedef float  f32x4  __attribute__((ext_vector_type(4)));

#define NHEADS 192   // B*G*H = 4*6*8
#define SEQ    1024
#define DKH    64
#define DMODEL 512

// ---------------- K1: fused QKV projection (fp32 in -> bf16 head-major out) ----
// y[m,n] = sum_k X[m,k] * W[n,k] + b[n];  m=(bg,s), n=(h,d)
// out layout: [bg*8+h][s][d] bf16
__global__ __launch_bounds__(256)
void proj_kernel(const float* __restrict__ X0, const float* __restrict__ X1,
                 const float* __restrict__ X2,
                 const float* __restrict__ W0, const float* __restrict__ W1,
                 const float* __restrict__ W2,
                 const float* __restrict__ B0, const float* __restrict__ B1,
                 const float* __restrict__ B2,
                 bf16_t* __restrict__ outbase)
{
    const int z = blockIdx.z;
    const float* X  = (z == 0) ? X0 : (z == 1) ? X1 : X2;
    const float* W  = (z == 0) ? W0 : (z == 1) ? W1 : W2;
    const float* Bi = (z == 0) ? B0 : (z == 1) ? B1 : B2;
    bf16_t* out = outbase + (size_t)z * ((size_t)NHEADS * SEQ * DKH);

    // +8 pad (stride 40 elems = 80 B): frag ds_read_b128 lands 2-way on banks (free)
    __shared__ bf16_t As[128][40];
    __shared__ bf16_t Bs[128][40];

    const int tid  = threadIdx.x;
    const int lane = tid & 63;
    const int w    = tid >> 6;
    const int wm   = w & 1, wn = w >> 1;
    const int l16  = lane & 15, quad = lane >> 4;
    const int m0   = blockIdx.x * 128;
    const int n0   = blockIdx.y * 128;

    f32x4 acc[4][4];
    const f32x4 vzero = {0.f, 0.f, 0.f, 0.f};
    #pragma unroll
    for (int i = 0; i < 4; ++i)
        #pragma unroll
        for (int j = 0; j < 4; ++j) acc[i][j] = vzero;

    for (int kt = 0; kt < 16; ++kt) {
        const int kbase = kt * 32;
        #pragma unroll
        for (int i = 0; i < 4; ++i) {
            int linear = i * 256 + tid;
            int row = linear >> 3;          // 0..127
            int c4  = (linear & 7) << 2;    // 0,4,...,28
            const float4 xv = *(const float4*)(X + (size_t)(m0 + row) * DMODEL + kbase + c4);
            bf16x4 xb = { (bf16_t)xv.x, (bf16_t)xv.y, (bf16_t)xv.z, (bf16_t)xv.w };
            *(bf16x4*)(&As[row][c4]) = xb;
            const float4 wv = *(const float4*)(W + (size_t)(n0 + row) * DMODEL + kbase + c4);
            bf16x4 wb = { (bf16_t)wv.x, (bf16_t)wv.y, (bf16_t)wv.z, (bf16_t)wv.w };
            *(bf16x4*)(&Bs[row][c4]) = wb;
        }
        __syncthreads();
        bf16x8 af[4], bfr[4];
        #pragma unroll
        for (int mt = 0; mt < 4; ++mt)
            af[mt] = *(const bf16x8*)(&As[wm*64 + mt*16 + l16][quad*8]);
        #pragma unroll
        for (int nt = 0; nt < 4; ++nt)
            bfr[nt] = *(const bf16x8*)(&Bs[wn*64 + nt*16 + l16][quad*8]);
        #pragma unroll
        for (int mt = 0; mt < 4; ++mt)
            #pragma unroll
            for (int nt = 0; nt < 4; ++nt)
                acc[mt][nt] = __builtin_amdgcn_mfma_f32_16x16x32_bf16(af[mt], bfr[nt], acc[mt][nt], 0, 0, 0);
        __syncthreads();
    }

    float bv[4];
    #pragma unroll
    for (int nt = 0; nt < 4; ++nt) bv[nt] = Bi[n0 + wn*64 + nt*16 + l16];

    #pragma unroll
    for (int mt = 0; mt < 4; ++mt) {
        #pragma unroll
        for (int nt = 0; nt < 4; ++nt) {
            #pragma unroll
            for (int r = 0; r < 4; ++r) {
                int m = m0 + wm*64 + mt*16 + quad*4 + r;  // C row = quad*4+reg
                int n = n0 + wn*64 + nt*16 + l16;         // C col = lane&15
                int bg = m >> 10, s = m & 1023;
                int h  = n >> 6,  d = n & 63;
                out[((size_t)(bg*8 + h) * SEQ + s) * DKH + d] = (bf16_t)(acc[mt][nt][r] + bv[nt]);
            }
        }
    }
}

// ---------------- K2: scores + softmax + write p + column-sum partials --------
// 1-D grid of 12288 blocks, XCD-swizzled: XCD x owns heads [x*24, x*24+24);
// within an XCD consecutive blocks are consecutive qb of the same head, so each
// head's K panel (128 KB) stays L2-resident across its 64 qb blocks.
// block 256 = 4 waves, wave w owns k-cols [w*256, w*256+256)
__global__ __launch_bounds__(256)
void attn_kernel(const bf16_t* __restrict__ Qb, const bf16_t* __restrict__ Kb,
                 float* __restrict__ pout, float* __restrict__ colpart)
{
    const int bid  = blockIdx.x;               // 0..12287
    const int wgid = (bid & 7) * 1536 + (bid >> 3);   // bijective XCD chunking
    const int head = wgid >> 6;                // 0..191
    const int qb   = wgid & 63;                // 0..63
    const int tid  = threadIdx.x;
    const int lane = tid & 63;
    const int w    = tid >> 6;
    const int l16  = lane & 15, quad = lane >> 4;

    // A fragments (Q rows qb*16..+15) straight from global: A[m=l16][k=quad*8+j]
    const bf16_t* qptr = Qb + ((size_t)head * SEQ + qb*16 + l16) * DKH + quad*8;
    const bf16x8 af0 = *(const bf16x8*)qptr;
    const bf16x8 af1 = *(const bf16x8*)(qptr + 32);

    f32x4 acc[16];
    const bf16_t* kbase = Kb + ((size_t)head * SEQ + w*256 + l16) * DKH + quad*8;
    const f32x4 vzero = {0.f, 0.f, 0.f, 0.f};
    #pragma unroll 8
    for (int t = 0; t < 16; ++t) {
        const bf16_t* kp = kbase + (size_t)t * 16 * DKH;
        bf16x8 b0 = *(const bf16x8*)kp;
        bf16x8 b1 = *(const bf16x8*)(kp + 32);
        f32x4 a = vzero;
        a = __builtin_amdgcn_mfma_f32_16x16x32_bf16(af0, b0, a, 0, 0, 0);
        a = __builtin_amdgcn_mfma_f32_16x16x32_bf16(af1, b1, a, 0, 0, 0);
        acc[t] = a;
    }

    // p_unnorm = exp(qk / (8*150)) = exp2(qk * log2e/1200); logits tiny -> no max needed
    const float C = 0.0012022458674074694f;
    #pragma unroll
    for (int t = 0; t < 16; ++t)
        #pragma unroll
        for (int r = 0; r < 4; ++r)
            acc[t][r] = exp2f(acc[t][r] * C);

    // row sums over this wave's 256 cols; rows are quad*4+r
    float rs[4];
    #pragma unroll
    for (int r = 0; r < 4; ++r) {
        float s = 0.f;
        #pragma unroll
        for (int t = 0; t < 16; ++t) s += acc[t][r];
        #pragma unroll
        for (int m = 1; m < 16; m <<= 1) s += __shfl_xor(s, m, 64);
        rs[r] = s;
    }
    __shared__ float rsLds[4][16];
    if (l16 == 0) {
        #pragma unroll
        for (int r = 0; r < 4; ++r) rsLds[w][quad*4 + r] = rs[r];
    }
    __syncthreads();
    float inv[4];
    #pragma unroll
    for (int r = 0; r < 4; ++r) {
        float tot = rsLds[0][quad*4+r] + rsLds[1][quad*4+r]
                  + rsLds[2][quad*4+r] + rsLds[3][quad*4+r];
        inv[r] = 1.0f / tot;
    }

    // write p and 16-row column partial sums
    float* prow = pout + ((size_t)head << 20) + (size_t)(qb*16 + quad*4) * SEQ + w*256 + l16;
    #pragma unroll
    for (int t = 0; t < 16; ++t) {
        float p0 = acc[t][0]*inv[0], p1 = acc[t][1]*inv[1];
        float p2 = acc[t][2]*inv[2], p3 = acc[t][3]*inv[3];
        prow[t*16 + 0*SEQ] = p0;
        prow[t*16 + 1*SEQ] = p1;
        prow[t*16 + 2*SEQ] = p2;
        prow[t*16 + 3*SEQ] = p3;
        float cs = p0 + p1 + p2 + p3;
        cs += __shfl_xor(cs, 16, 64);
        cs += __shfl_xor(cs, 32, 64);
        if (quad == 0)
            colpart[((size_t)(head*64 + qb) << 10) + w*256 + t*16 + l16] = cs;
    }
}

// ---------------- K3: reduce column partials -> pmean; out = pmean @ V --------
__global__ __launch_bounds__(256)
void reduce_kernel(const float* __restrict__ colpart, const bf16_t* __restrict__ Vb,
                   float* __restrict__ outv)
{
    const int head = blockIdx.x;
    const int tid  = threadIdx.x;
    __shared__ float pmean[1024];
    float s0 = 0.f, s1 = 0.f, s2 = 0.f, s3 = 0.f;
    const float* cp = colpart + ((size_t)(head*64) << 10);
    for (int qb = 0; qb < 64; ++qb) {
        const float* row = cp + (qb << 10);
        s0 += row[tid];
        s1 += row[tid + 256];
        s2 += row[tid + 512];
        s3 += row[tid + 768];
    }
    const float sc = 1.0f / 1024.0f;   // mean over q
    pmean[tid]       = s0 * sc;
    pmean[tid + 256] = s1 * sc;
    pmean[tid + 512] = s2 * sc;
    pmean[tid + 768] = s3 * sc;
    __syncthreads();

    const int d  = tid & 63;
    const int kp = tid >> 6;
    const bf16_t* vb = Vb + (size_t)head * SEQ * DKH;
    float a = 0.f;
    for (int k = kp*256; k < kp*256 + 256; ++k)
        a += pmean[k] * (float)vb[k*DKH + d];
    __shared__ float red[4][64];
    red[kp][d] = a;
    __syncthreads();
    if (tid < 64)
        outv[head*64 + tid] = red[0][tid] + red[1][tid] + red[2][tid] + red[3][tid];
}

// ---------------- K4: y = concat_transposed(out) @ Wo^T + bo ------------------
// x2[c] = out[bg][h=c&7][d=c>>3]  (matches ref transpose(0,1,3,2).reshape)
__global__ __launch_bounds__(256)
void oproj_kernel(const float* __restrict__ outv, const float* __restrict__ Wo,
                  const float* __restrict__ bo, float* __restrict__ y)
{
    const int bg   = blockIdx.x;
    const int tid  = threadIdx.x;
    const int lane = tid & 63, w = tid >> 6;
    __shared__ float x2[512];
    for (int c = tid; c < 512; c += 256)
        x2[c] = outv[bg*512 + ((c & 7) << 6) + (c >> 3)];
    __syncthreads();
    float xv[8];
    #pragma unroll
    for (int j = 0; j < 8; ++j) xv[j] = x2[lane*8 + j];
    for (int e = w*128; e < w*128 + 128; ++e) {
        const float* wr = Wo + (size_t)e * 512 + lane*8;
        float a = 0.f;
        #pragma unroll
        for (int j = 0; j < 8; ++j) a += xv[j] * wr[j];
        #pragma unroll
        for (int m = 32; m >= 1; m >>= 1) a += __shfl_xor(a, m, 64);
        if (lane == 0) y[bg*512 + e] = a + bo[e];
    }
}

extern "C" void kernel_launch(void* const* d_in, const int* in_sizes, int n_in,
                              void* d_out, int out_size, void* d_ws, size_t ws_size,
                              hipStream_t stream)
{
    const float* q  = (const float*)d_in[0];
    const float* k  = (const float*)d_in[1];
    const float* v  = (const float*)d_in[2];
    const float* Wq = (const float*)d_in[3];
    const float* bq = (const float*)d_in[4];
    const float* Wk = (const float*)d_in[5];
    const float* bk = (const float*)d_in[6];
    const float* Wv = (const float*)d_in[7];
    const float* bv = (const float*)d_in[8];
    const float* Wo = (const float*)d_in[9];
    const float* bo = (const float*)d_in[10];
    float* out = (float*)d_out;

    // ws layout: qkv bf16 3x24MB | colpart f32 48MB | outv f32 48KB  (~120 MB)
    char* ws = (char*)d_ws;
    bf16_t* qkv    = (bf16_t*)ws;
    float* colpart = (float*)(ws + 75497472ull);
    float* outv    = (float*)(ws + 125829120ull);
    const size_t projElems = (size_t)NHEADS * SEQ * DKH;  // 12,582,912

    proj_kernel<<<dim3(192, 4, 3), 256, 0, stream>>>(q, k, v, Wq, Wk, Wv, bq, bk, bv, qkv);
    attn_kernel<<<dim3(12288), 256, 0, stream>>>(qkv, qkv + projElems, out + 12288, colpart);
    reduce_kernel<<<192, 256, 0, stream>>>(colpart, qkv + 2*projElems, outv);
    oproj_kernel<<<24, 256, 0, stream>>>(outv, Wo, bo, out);
}